// Round 1
// baseline (144.834 us; speedup 1.0000x reference)
//
#include <hip/hip_runtime.h>
#include <hip/hip_bf16.h>

#define BB 64
#define TT 256
#define DD 128
#define HH 8
#define HE 1024   // H*E

// One block per batch element b. 256 threads.
// Pipeline (all through LDS, algebraically collapsed — see analysis):
//   xw[d]    = sum_j Ws[j] * x[b,j,d]
//   Kw[he]   = xw @ Wk[:,he] + Sw*bk[he]          (Sw = sum_j Ws[j])
//   wqk[h,d] = sum_e Wq[d, h*128+e] * Kw[h,e]     (bq/bs drop: softmax shift-invariant)
//   s[h,t]   = scale * x[b,t] . wqk[h]            -> softmax over t -> beta[h,t]
//   xb[h,d]  = sum_t beta[h,t] * x[b,t,d]
//   res[he]  = xb[h] @ Wv[:,he] + bv[he]          (sum beta = 1)
//   out[b,d] = res @ Wo[:,d] + bo[d]
__global__ __launch_bounds__(256)
void ta_fused_kernel(const float* __restrict__ x,
                     const float* __restrict__ Wq,
                     const float* __restrict__ Wk, const float* __restrict__ bk,
                     const float* __restrict__ Wv, const float* __restrict__ bv,
                     const float* __restrict__ Ws,
                     const float* __restrict__ Wo, const float* __restrict__ bo,
                     float* __restrict__ out)
{
    __shared__ float ws_s[TT];
    __shared__ float sw_s;
    __shared__ float xw_s[DD];
    __shared__ float kw_s[HE];
    __shared__ float wqk_s[HE];
    __shared__ float sm_s[TT][HH + 1];   // summary then beta, padded
    __shared__ float p2_s[2][HH][DD];    // two-half partials (phase1 reuses [.][0][.])
    __shared__ float xb_s[HH][DD];
    __shared__ float res_s[HE];
    __shared__ float po_s[2][DD];

    const int tid  = threadIdx.x;
    const int b    = blockIdx.x;
    const int d    = tid & 127;
    const int half = tid >> 7;
    const float* xb_ptr = x + (size_t)b * TT * DD;

    // ---- Phase 0: Ws -> LDS, Sw = sum(Ws)
    ws_s[tid] = Ws[tid];
    __syncthreads();
    if (tid < 64) {
        float v = ws_s[tid] + ws_s[tid + 64] + ws_s[tid + 128] + ws_s[tid + 192];
        #pragma unroll
        for (int off = 32; off; off >>= 1) v += __shfl_xor(v, off, 64);
        if (tid == 0) sw_s = v;
    }
    // (sw_s consumed after phase-1 barrier)

    // ---- Phase 1: xw[d] = sum_j Ws[j]*x[b,j,d]
    {
        float acc = 0.f;
        const float* xp = xb_ptr + (size_t)(half * 128) * DD + d;
        #pragma unroll 8
        for (int j = 0; j < 128; ++j) acc += ws_s[half * 128 + j] * xp[(size_t)j * DD];
        p2_s[half][0][d] = acc;
        __syncthreads();
        if (tid < DD) xw_s[tid] = p2_s[0][0][tid] + p2_s[1][0][tid];
        __syncthreads();
    }

    // ---- Phase 2: Kw[he] = xw @ Wk[:,he] + Sw*bk[he]
    {
        const float sw = sw_s;
        float a0 = sw * bk[tid];
        float a1 = sw * bk[tid + 256];
        float a2 = sw * bk[tid + 512];
        float a3 = sw * bk[tid + 768];
        #pragma unroll 4
        for (int dd = 0; dd < DD; ++dd) {
            const float xv = xw_s[dd];
            const float* wr = Wk + (size_t)dd * HE;
            a0 += xv * wr[tid];
            a1 += xv * wr[tid + 256];
            a2 += xv * wr[tid + 512];
            a3 += xv * wr[tid + 768];
        }
        kw_s[tid] = a0; kw_s[tid + 256] = a1; kw_s[tid + 512] = a2; kw_s[tid + 768] = a3;
        __syncthreads();
    }

    // ---- Phase 3: wqk[h,d] = sum_e Wq[d, h*128+e]*Kw[h,e]
    {
        #pragma unroll
        for (int k = 0; k < 4; ++k) {
            const int oi = tid + 256 * k;
            const int h  = oi >> 7, dd = oi & 127;
            const float4* wr  = (const float4*)(Wq + (size_t)dd * HE + h * 128);
            const float4* kwp = (const float4*)(kw_s + h * 128);
            float a = 0.f;
            #pragma unroll 8
            for (int e4 = 0; e4 < 32; ++e4) {
                const float4 w = wr[e4];
                const float4 c = kwp[e4];
                a += w.x * c.x + w.y * c.y + w.z * c.z + w.w * c.w;
            }
            wqk_s[oi] = a;
        }
        __syncthreads();
    }

    // ---- Phase 4: summary + softmax over t (thread tid == t)
    {
        float acc[HH];
        #pragma unroll
        for (int h = 0; h < HH; ++h) acc[h] = 0.f;
        const float4* xr = (const float4*)(xb_ptr + (size_t)tid * DD);
        #pragma unroll 4
        for (int d4 = 0; d4 < 32; ++d4) {
            const float4 xv = xr[d4];
            #pragma unroll
            for (int h = 0; h < HH; ++h) {
                const float4 w = ((const float4*)(wqk_s + h * 128))[d4];
                acc[h] += xv.x * w.x + xv.y * w.y + xv.z * w.z + xv.w * w.w;
            }
        }
        const float scale = 0.08838834764831845f;  // 1/sqrt(128)
        #pragma unroll
        for (int h = 0; h < HH; ++h) sm_s[tid][h] = acc[h] * scale;
        __syncthreads();

        const int wave = tid >> 6, lane = tid & 63;
        for (int h = wave; h < HH; h += 4) {
            float v0 = sm_s[lane][h], v1 = sm_s[lane + 64][h];
            float v2 = sm_s[lane + 128][h], v3 = sm_s[lane + 192][h];
            float m = fmaxf(fmaxf(v0, v1), fmaxf(v2, v3));
            #pragma unroll
            for (int off = 32; off; off >>= 1) m = fmaxf(m, __shfl_xor(m, off, 64));
            float e0 = __expf(v0 - m), e1 = __expf(v1 - m);
            float e2 = __expf(v2 - m), e3 = __expf(v3 - m);
            float s = e0 + e1 + e2 + e3;
            #pragma unroll
            for (int off = 32; off; off >>= 1) s += __shfl_xor(s, off, 64);
            const float inv = 1.f / s;
            sm_s[lane][h] = e0 * inv; sm_s[lane + 64][h] = e1 * inv;
            sm_s[lane + 128][h] = e2 * inv; sm_s[lane + 192][h] = e3 * inv;
        }
        __syncthreads();
    }

    // ---- Phase 5: xb[h,d] = sum_t beta[h,t]*x[b,t,d]
    {
        float acc[HH];
        #pragma unroll
        for (int h = 0; h < HH; ++h) acc[h] = 0.f;
        const float* xp = xb_ptr + (size_t)(half * 128) * DD + d;
        #pragma unroll 4
        for (int j = 0; j < 128; ++j) {
            const float xv = xp[(size_t)j * DD];
            const int t = half * 128 + j;
            #pragma unroll
            for (int h = 0; h < HH; ++h) acc[h] += sm_s[t][h] * xv;
        }
        #pragma unroll
        for (int h = 0; h < HH; ++h) p2_s[half][h][d] = acc[h];
        __syncthreads();
        #pragma unroll
        for (int k = 0; k < 4; ++k) {
            const int oi = tid + 256 * k;
            const int h = oi >> 7, dd = oi & 127;
            xb_s[h][dd] = p2_s[0][h][dd] + p2_s[1][h][dd];
        }
        __syncthreads();
    }

    // ---- Phase 6: res[he] = xb[h] @ Wv[:,he] + bv[he]
    {
        float a[4];
        #pragma unroll
        for (int k = 0; k < 4; ++k) a[k] = bv[tid + 256 * k];
        #pragma unroll 4
        for (int dd = 0; dd < DD; ++dd) {
            const float* wr = Wv + (size_t)dd * HE;
            #pragma unroll
            for (int k = 0; k < 4; ++k) {
                const int he = tid + 256 * k;
                a[k] += xb_s[he >> 7][dd] * wr[he];
            }
        }
        #pragma unroll
        for (int k = 0; k < 4; ++k) res_s[tid + 256 * k] = a[k];
        __syncthreads();
    }

    // ---- Phase 7: out[b,d] = res @ Wo[:,d] + bo[d]
    {
        float acc = (half == 0) ? bo[d] : 0.f;
        #pragma unroll 8
        for (int j = 0; j < 512; ++j) {
            const int he = half * 512 + j;
            acc += res_s[he] * Wo[(size_t)he * DD + d];
        }
        po_s[half][d] = acc;
        __syncthreads();
        if (tid < DD) out[(size_t)b * DD + tid] = po_s[0][tid] + po_s[1][tid];
    }
}

extern "C" void kernel_launch(void* const* d_in, const int* in_sizes, int n_in,
                              void* d_out, int out_size, void* d_ws, size_t ws_size,
                              hipStream_t stream) {
    const float* x  = (const float*)d_in[0];
    const float* Wq = (const float*)d_in[1];
    // d_in[2] = bq  — softmax shift-invariant, unused
    const float* Wk = (const float*)d_in[3];
    const float* bk = (const float*)d_in[4];
    const float* Wv = (const float*)d_in[5];
    const float* bv = (const float*)d_in[6];
    const float* Ws = (const float*)d_in[7];
    // d_in[8] = bs  — softmax shift-invariant, unused
    const float* Wo = (const float*)d_in[9];
    const float* bo = (const float*)d_in[10];
    float* out = (float*)d_out;

    hipLaunchKernelGGL(ta_fused_kernel, dim3(BB), dim3(256), 0, stream,
                       x, Wq, Wk, bk, Wv, bv, Ws, Wo, bo, out);
}

// Round 2
// 132.362 us; speedup vs baseline: 1.0942x; 1.0942x over previous
//
#include <hip/hip_runtime.h>
#include <hip/hip_bf16.h>

// Problem constants: B=64, T=256, D=128, H=8, E=128, H*E=1024.
// Algebra (verified round 1): with xw[b]=Ws^T x[b], Sw=sum(Ws):
//   Kw[b,he]  = xw[b] @ Wk[:,he] + Sw*bk[he]
//   wqk[b,h,d]= scale * sum_e Wq[d,h*128+e]*Kw[b,h,e]     (bq, bs drop: softmax shift-invariant)
//   beta[b,h,t] = softmax_t( x[b,t] . wqk[b,h] )
//   xb[b,h,d] = sum_t beta[b,h,t]*x[b,t,d]
//   res[b,he] = xb[b,h] @ Wv[:,he] + bv[he]               (sum_t beta = 1)
//   out[b,d'] = res[b] @ Wo[:,d'] + bo[d']
//
// Design rule this round: wave-uniform small operands live in GLOBAL ws and are
// read with uniform indices -> compiler emits s_load (SMEM pipe, no LDS storms).
// Weight matrices are streamed with lane-coalesced independent loads.

#define XW_OFF   0        // [64][144]  (slot 128 = Sw), 144 stride keeps 16B align
#define KW_OFF   9216     // [64][1024]
#define WQK_OFF  74752    // [64][1024] (pre-scaled)
#define BETA_OFF 140288   // [64][256][8]
#define XB_OFF   271360   // [64][1024]
#define RES_OFF  336896   // [64][1024]
// total 402432 floats = 1.61 MB of d_ws

#define SCALE 0.08838834764831845f  // 1/sqrt(128)

// K1: xw[b,d] = sum_t Ws[t]*x[b,t,d]; also Sw. grid 64, block 512.
__global__ __launch_bounds__(512)
void k_xw(const float* __restrict__ x, const float* __restrict__ Wsv,
          float* __restrict__ xwg)
{
    __shared__ float p[4][128];
    const int tid = threadIdx.x, d = tid & 127, q = tid >> 7, b = blockIdx.x;
    const float* xp = x + (size_t)b * 32768 + d;
    float acc = 0.f;
    #pragma unroll 16
    for (int j = 0; j < 64; ++j) {
        const int t = q * 64 + j;
        acc += Wsv[t] * xp[(size_t)t * 128];   // Wsv[t] uniform -> s_load
    }
    p[q][d] = acc;
    __syncthreads();
    if (tid < 128) {
        xwg[b * 144 + tid] = p[0][tid] + p[1][tid] + p[2][tid] + p[3][tid];
    } else if (tid < 192) {            // wave 2 computes Sw
        const int lane = tid & 63;
        float v = Wsv[lane] + Wsv[lane + 64] + Wsv[lane + 128] + Wsv[lane + 192];
        #pragma unroll
        for (int off = 32; off; off >>= 1) v += __shfl_xor(v, off, 64);
        if (lane == 0) xwg[b * 144 + 128] = v;
    }
}

// K2: Kw[b,he] = sum_k xw[k]*Wk[k,he] + Sw*bk[he]. grid (64,4), block 256.
__global__ __launch_bounds__(256)
void k_kw(const float* __restrict__ Wk, const float* __restrict__ bk,
          const float* __restrict__ xwg, float* __restrict__ kw)
{
    const int b = blockIdx.x;
    const int he = blockIdx.y * 256 + threadIdx.x;
    const float* xwp = xwg + b * 144;              // uniform -> s_load
    float acc = xwp[128] * bk[he];                 // Sw*bk
    #pragma unroll 32
    for (int k = 0; k < 128; ++k)
        acc += xwp[k] * Wk[(size_t)k * 1024 + he]; // coalesced 256B/wave-instr
    kw[b * 1024 + he] = acc;
}

// K3: wqk[b,h,d] = scale*sum_e Wq[d,h*128+e]*Kw[b,h,e]. grid (64,4), block 256.
__global__ __launch_bounds__(256)
void k_wqk(const float* __restrict__ Wq, const float* __restrict__ kw,
           float* __restrict__ wqk)
{
    const int b = blockIdx.x;
    const int oi = blockIdx.y * 256 + threadIdx.x;
    const int h = oi >> 7, d = oi & 127;           // h uniform per wave
    const float4* wq4 = (const float4*)(Wq + (size_t)d * 1024 + h * 128);
    const float* kwp = kw + b * 1024 + h * 128;    // uniform -> s_load
    float a = 0.f;
    #pragma unroll 8
    for (int j = 0; j < 32; ++j) {
        const float4 w = wq4[j];
        a += w.x * kwp[4*j] + w.y * kwp[4*j+1] + w.z * kwp[4*j+2] + w.w * kwp[4*j+3];
    }
    wqk[b * 1024 + oi] = a * SCALE;
}

// K4: scores + softmax over t -> beta[b,t,0..7]. grid 64, block 256 (thread=t).
__global__ __launch_bounds__(256)
void k_beta(const float* __restrict__ x, const float* __restrict__ wqk,
            float* __restrict__ beta)
{
    __shared__ float sm[256][9];
    const int t = threadIdx.x, b = blockIdx.x;
    const float4* xr4 = (const float4*)(x + (size_t)b * 32768 + (size_t)t * 128);
    float4 xr[32];
    #pragma unroll
    for (int j = 0; j < 32; ++j) xr[j] = xr4[j];
    const float* wq = wqk + b * 1024;
    #pragma unroll
    for (int h = 0; h < 8; ++h) {
        const float4* w4 = (const float4*)(wq + h * 128); // uniform -> s_load
        float a = 0.f;
        #pragma unroll
        for (int j = 0; j < 32; ++j) {
            const float4 w = w4[j];
            a += xr[j].x * w.x + xr[j].y * w.y + xr[j].z * w.z + xr[j].w * w.w;
        }
        sm[t][h] = a;   // already scaled (folded into wqk)
    }
    __syncthreads();
    const int wid = t >> 6, lane = t & 63;
    for (int hh = wid; hh < 8; hh += 4) {
        float v0 = sm[lane][hh],       v1 = sm[lane + 64][hh];
        float v2 = sm[lane + 128][hh], v3 = sm[lane + 192][hh];
        float m = fmaxf(fmaxf(v0, v1), fmaxf(v2, v3));
        #pragma unroll
        for (int off = 32; off; off >>= 1) m = fmaxf(m, __shfl_xor(m, off, 64));
        float e0 = __expf(v0 - m), e1 = __expf(v1 - m);
        float e2 = __expf(v2 - m), e3 = __expf(v3 - m);
        float s = e0 + e1 + e2 + e3;
        #pragma unroll
        for (int off = 32; off; off >>= 1) s += __shfl_xor(s, off, 64);
        const float inv = 1.f / s;
        sm[lane][hh] = e0 * inv;        sm[lane + 64][hh] = e1 * inv;
        sm[lane + 128][hh] = e2 * inv;  sm[lane + 192][hh] = e3 * inv;
    }
    __syncthreads();
    float4 b0, b1;
    b0.x = sm[t][0]; b0.y = sm[t][1]; b0.z = sm[t][2]; b0.w = sm[t][3];
    b1.x = sm[t][4]; b1.y = sm[t][5]; b1.z = sm[t][6]; b1.w = sm[t][7];
    float4* bo4 = (float4*)(beta + b * 2048 + t * 8);
    bo4[0] = b0; bo4[1] = b1;
}

// K5: xb[b,h,d] = sum_t beta[b,h,t]*x[b,t,d]. grid 64, block 512.
__global__ __launch_bounds__(512)
void k_xb(const float* __restrict__ x, const float* __restrict__ beta,
          float* __restrict__ xb)
{
    __shared__ float p[4 * 1024];
    const int tid = threadIdx.x, d = tid & 127, tc = tid >> 7, b = blockIdx.x;
    const float* xp = x + (size_t)b * 32768 + d;
    const float* bp = beta + b * 2048;
    float a0=0,a1=0,a2=0,a3=0,a4=0,a5=0,a6=0,a7=0;
    #pragma unroll 8
    for (int j = 0; j < 64; ++j) {
        const int t = tc * 64 + j;
        const float xv = xp[(size_t)t * 128];                       // coalesced
        const float4 ba = *(const float4*)(bp + t * 8);             // uniform -> s_load
        const float4 bb = *(const float4*)(bp + t * 8 + 4);
        a0 += ba.x * xv; a1 += ba.y * xv; a2 += ba.z * xv; a3 += ba.w * xv;
        a4 += bb.x * xv; a5 += bb.y * xv; a6 += bb.z * xv; a7 += bb.w * xv;
    }
    float acc[8] = {a0,a1,a2,a3,a4,a5,a6,a7};
    #pragma unroll
    for (int h = 0; h < 8; ++h) p[tc * 1024 + h * 128 + d] = acc[h];
    __syncthreads();
    #pragma unroll
    for (int oi = tid; oi < 1024; oi += 512)
        xb[b * 1024 + oi] = p[oi] + p[1024 + oi] + p[2048 + oi] + p[3072 + oi];
}

// K6: res[b,he] = sum_d xb[b,h,d]*Wv[d,he] + bv[he]. grid (64,4), block 256.
__global__ __launch_bounds__(256)
void k_res(const float* __restrict__ Wv, const float* __restrict__ bv,
           const float* __restrict__ xb, float* __restrict__ res)
{
    const int b = blockIdx.x;
    const int he = blockIdx.y * 256 + threadIdx.x;
    const int h = he >> 7;                          // uniform per wave
    const float* xbp = xb + b * 1024 + h * 128;     // uniform -> s_load
    float acc = bv[he];
    #pragma unroll 32
    for (int dd = 0; dd < 128; ++dd)
        acc += xbp[dd] * Wv[(size_t)dd * 1024 + he];
    res[b * 1024 + he] = acc;
}

// K7: out[b,d'] = sum_he res[b,he]*Wo[he,d'] + bo[d']. grid 64, block 1024.
__global__ __launch_bounds__(1024)
void k_out(const float* __restrict__ Wo, const float* __restrict__ bov,
           const float* __restrict__ res, float* __restrict__ out)
{
    __shared__ float p[8][128];
    const int tid = threadIdx.x, d = tid & 127, oc = tid >> 7, b = blockIdx.x;
    const float* rp = res + b * 1024 + oc * 128;    // uniform per wave -> s_load
    float acc = 0.f;
    #pragma unroll 32
    for (int j = 0; j < 128; ++j)
        acc += rp[j] * Wo[(size_t)(oc * 128 + j) * 128 + d];
    p[oc][d] = acc;
    __syncthreads();
    if (tid < 128) {
        float v = bov[tid];
        #pragma unroll
        for (int o = 0; o < 8; ++o) v += p[o][tid];
        out[(size_t)b * 128 + tid] = v;
    }
}

extern "C" void kernel_launch(void* const* d_in, const int* in_sizes, int n_in,
                              void* d_out, int out_size, void* d_ws, size_t ws_size,
                              hipStream_t stream) {
    const float* x  = (const float*)d_in[0];
    const float* Wq = (const float*)d_in[1];
    // d_in[2] = bq  — softmax shift-invariant, unused
    const float* Wk = (const float*)d_in[3];
    const float* bk = (const float*)d_in[4];
    const float* Wv = (const float*)d_in[5];
    const float* bv = (const float*)d_in[6];
    const float* Ws = (const float*)d_in[7];
    // d_in[8] = bs  — softmax shift-invariant, unused
    const float* Wo = (const float*)d_in[9];
    const float* bo = (const float*)d_in[10];
    float* out = (float*)d_out;
    float* ws  = (float*)d_ws;

    k_xw  <<<dim3(64),    dim3(512),  0, stream>>>(x, Ws, ws + XW_OFF);
    k_kw  <<<dim3(64, 4), dim3(256),  0, stream>>>(Wk, bk, ws + XW_OFF, ws + KW_OFF);
    k_wqk <<<dim3(64, 4), dim3(256),  0, stream>>>(Wq, ws + KW_OFF, ws + WQK_OFF);
    k_beta<<<dim3(64),    dim3(256),  0, stream>>>(x, ws + WQK_OFF, ws + BETA_OFF);
    k_xb  <<<dim3(64),    dim3(512),  0, stream>>>(x, ws + BETA_OFF, ws + XB_OFF);
    k_res <<<dim3(64, 4), dim3(256),  0, stream>>>(Wv, bv, ws + XB_OFF, ws + RES_OFF);
    k_out <<<dim3(64),    dim3(1024), 0, stream>>>(Wo, bo, ws + RES_OFF, out);
}

// Round 3
// 102.023 us; speedup vs baseline: 1.4196x; 1.2974x over previous
//
#include <hip/hip_runtime.h>
#include <hip/hip_bf16.h>

// B=64, T=256, D=128, H=8, E=128, H*E=1024.
// Algebra (verified R1): with xw[b]=Ws^T x[b], Sw=sum(Ws):
//   Kw[b,he]   = xw[b] @ Wk[:,he] + Sw*bk[he]
//   wqk[b,h,d] = scale * sum_e Wq[d,h*128+e]*Kw[b,h,e]   (bq, bs drop: shift-invariant)
//   beta[b,h,t]= softmax_t( x[b,t] . wqk[b,h] )
//   xb[b,h,d]  = sum_t beta[b,h,t]*x[b,t,d]
//   res[b,he]  = xb[b,h] @ Wv[:,he] + bv[he]             (sum_t beta = 1)
//   out[b,d']  = res[b] @ Wo[:,d'] + bo[d']
//
// R3 design: 2 kernels + memset(out). k_bh: one block per (b, head-pair),
// full chain to xb. k_ov: res+out partials with atomicAdd. Small operands
// cross via d_ws with wave-uniform indices -> s_load (SMEM pipe).

#define SCALE 0.08838834764831845f  // 1/sqrt(128)

// ---------------- K_A: grid (64,4), block 512. heads h0=2p, h1=2p+1 --------
__global__ __launch_bounds__(512)
void k_bh(const float* __restrict__ x,  const float* __restrict__ Wq,
          const float* __restrict__ Wk, const float* __restrict__ bk,
          const float* __restrict__ Wsv, float* __restrict__ xbg)
{
    __shared__ float red[4][256];      // generic partial buffer
    __shared__ float xwS[128];
    __shared__ float kwS[256];         // [hi][e]
    __shared__ float wqkS[256];        // [hi][d], pre-scaled
    __shared__ float betaS[2][256];    // [hi][t]
    __shared__ float smx[2][4], sms[2][4];
    __shared__ float swS;

    const int tid = threadIdx.x;
    const int b = blockIdx.x, p = blockIdx.y;
    const float* xb_ptr = x + (size_t)b * 32768;

    // ---- Phase A: xw[d] = sum_t Ws[t]*x[b,t,d]; Sw.
    {
        const int d = tid & 127, tc = tid >> 7;              // tc in 0..3
        float acc = 0.f;
        const float* xp = xb_ptr + (size_t)(tc * 64) * 128 + d;
        #pragma unroll 16
        for (int j = 0; j < 64; ++j)
            acc += Wsv[tc * 64 + j] * xp[(size_t)j * 128];   // Ws uniform -> s_load
        red[tc][d] = acc;                                    // d<128: no overlap vs [128..255]
        if (tid >= 128 && tid < 192) {                       // one wave: Sw
            const int lane = tid & 63;
            float v = Wsv[lane] + Wsv[lane + 64] + Wsv[lane + 128] + Wsv[lane + 192];
            #pragma unroll
            for (int off = 32; off; off >>= 1) v += __shfl_xor(v, off, 64);
            if (lane == 0) swS = v;
        }
        __syncthreads();
        if (tid < 128) xwS[tid] = red[0][tid] + red[1][tid] + red[2][tid] + red[3][tid];
        __syncthreads();
    }

    // ---- Phase B: Kw (both heads). he = 256*p + e2, e2 = hi*128+e.
    {
        const int e2 = tid & 255, kh = tid >> 8;             // kh in 0..1
        const int he = 256 * p + e2;
        float acc = 0.f;
        const float* wp = Wk + (size_t)(kh * 64) * 1024 + he;
        #pragma unroll 16
        for (int j = 0; j < 64; ++j)
            acc += xwS[kh * 64 + j] * wp[(size_t)j * 1024];  // xwS wave-uniform bcast
        red[kh][e2] = acc;
        __syncthreads();
        if (tid < 256) kwS[tid] = red[0][tid] + red[1][tid] + swS * bk[256 * p + tid];
        __syncthreads();
    }

    // ---- Phase C: wqk (both heads). o = hi*128+d.
    {
        const int o = tid & 255, eh = tid >> 8;
        const int d = o & 127, hi = o >> 7;
        const float4* wq4 = (const float4*)(Wq + (size_t)d * 1024 + (2 * p + hi) * 128 + eh * 64);
        const float* kwp = kwS + hi * 128 + eh * 64;         // wave-uniform bcast
        float acc = 0.f;
        #pragma unroll
        for (int j4 = 0; j4 < 16; ++j4) {
            const float4 w = wq4[j4];
            acc += w.x * kwp[4*j4] + w.y * kwp[4*j4+1] + w.z * kwp[4*j4+2] + w.w * kwp[4*j4+3];
        }
        red[eh][o] = acc;
        __syncthreads();
        if (tid < 256) wqkS[tid] = (red[0][tid] + red[1][tid]) * SCALE;
        __syncthreads();
    }

    // ---- Phase D: scores for both heads, then softmax over t per head.
    {
        const int t = tid & 255, dh = tid >> 8;              // dh: which half of d
        const float4* xr4 = (const float4*)(xb_ptr + (size_t)t * 128 + dh * 64);
        float a0 = 0.f, a1 = 0.f;
        #pragma unroll
        for (int j4 = 0; j4 < 16; ++j4) {
            const float4 xv = xr4[j4];
            const float* w0 = wqkS + dh * 64 + 4 * j4;       // hi=0, wave-uniform
            const float* w1 = wqkS + 128 + dh * 64 + 4 * j4; // hi=1
            a0 += xv.x * w0[0] + xv.y * w0[1] + xv.z * w0[2] + xv.w * w0[3];
            a1 += xv.x * w1[0] + xv.y * w1[1] + xv.z * w1[2] + xv.w * w1[3];
        }
        red[dh][t] = a0; red[2 + dh][t] = a1;
        __syncthreads();

        const int hi = tid >> 8;                             // thread (t, hi)
        float s = red[hi * 2][t] + red[hi * 2 + 1][t];
        const int w = tid >> 6, wi = w & 3, lane = tid & 63;
        float m = s;
        #pragma unroll
        for (int off = 32; off; off >>= 1) m = fmaxf(m, __shfl_xor(m, off, 64));
        if (lane == 0) smx[hi][wi] = m;
        __syncthreads();
        const float M = fmaxf(fmaxf(smx[hi][0], smx[hi][1]), fmaxf(smx[hi][2], smx[hi][3]));
        const float e = __expf(s - M);
        float ss = e;
        #pragma unroll
        for (int off = 32; off; off >>= 1) ss += __shfl_xor(ss, off, 64);
        if (lane == 0) sms[hi][wi] = ss;
        __syncthreads();
        const float S = sms[hi][0] + sms[hi][1] + sms[hi][2] + sms[hi][3];
        betaS[hi][t] = e / S;
        __syncthreads();
    }

    // ---- Phase E: xb[hi][d] = sum_t beta[hi][t]*x[t][d], both heads.
    {
        const int d = tid & 127, tq = tid >> 7;              // tq in 0..3
        const float* xp = xb_ptr + (size_t)(tq * 64) * 128 + d;
        const float* b0 = betaS[0] + tq * 64;                // wave-uniform bcast
        const float* b1 = betaS[1] + tq * 64;
        float a0 = 0.f, a1 = 0.f;
        #pragma unroll 8
        for (int j = 0; j < 64; ++j) {
            const float xv = xp[(size_t)j * 128];            // coalesced
            a0 += b0[j] * xv; a1 += b1[j] * xv;
        }
        __syncthreads();                                     // red reuse
        red[tq][d] = a0; red[tq][128 + d] = a1;
        __syncthreads();
        if (tid < 256)                                       // o = hi*128+d -> he = 256p+o
            xbg[b * 1024 + 256 * p + tid] =
                red[0][tid] + red[1][tid] + red[2][tid] + red[3][tid];
    }
}

// ---------------- K_B: grid (64,4), block 256. he-chunk y --------------------
__global__ __launch_bounds__(256)
void k_ov(const float* __restrict__ Wv, const float* __restrict__ bv,
          const float* __restrict__ Wo, const float* __restrict__ bov,
          const float* __restrict__ xbg, float* __restrict__ out)
{
    __shared__ float resS[256];
    __shared__ float po[2][128];
    const int tid = threadIdx.x;
    const int b = blockIdx.x, y = blockIdx.y;
    const int he = y * 256 + tid;

    // res[he] = xb[b, he>>7] . Wv[:,he] + bv[he]
    {
        const float* xbp = xbg + b * 1024 + (he >> 7) * 128; // wave-uniform -> s_load
        float acc = bv[he];
        const float* wp = Wv + he;
        #pragma unroll 16
        for (int dd = 0; dd < 128; ++dd)
            acc += xbp[dd] * wp[(size_t)dd * 1024];          // coalesced
        resS[tid] = acc;
        __syncthreads();
    }

    // partial out[d] over this he-chunk; atomic-accumulate across y.
    {
        const int d = tid & 127, rh = tid >> 7;
        const float* rp = resS + rh * 128;                   // LDS bcast (uniform)
        const float* wp = Wo + (size_t)(y * 256 + rh * 128) * 128 + d;
        float acc = 0.f;
        #pragma unroll 16
        for (int j = 0; j < 128; ++j)
            acc += rp[j] * wp[(size_t)j * 128];              // coalesced
        po[rh][d] = acc;
        __syncthreads();
        if (tid < 128) {
            float v = po[0][tid] + po[1][tid];
            if (y == 0) v += bov[tid];
            atomicAdd(&out[(size_t)b * 128 + tid], v);
        }
    }
}

extern "C" void kernel_launch(void* const* d_in, const int* in_sizes, int n_in,
                              void* d_out, int out_size, void* d_ws, size_t ws_size,
                              hipStream_t stream) {
    const float* x  = (const float*)d_in[0];
    const float* Wq = (const float*)d_in[1];
    // d_in[2] = bq  — softmax shift-invariant, unused
    const float* Wk = (const float*)d_in[3];
    const float* bk = (const float*)d_in[4];
    const float* Wv = (const float*)d_in[5];
    const float* bv = (const float*)d_in[6];
    const float* Ws = (const float*)d_in[7];
    // d_in[8] = bs  — softmax shift-invariant, unused
    const float* Wo = (const float*)d_in[9];
    const float* bo = (const float*)d_in[10];
    float* out = (float*)d_out;
    float* ws  = (float*)d_ws;   // xb lives at ws[0 .. 64*1024)

    hipMemsetAsync(out, 0, (size_t)out_size * sizeof(float), stream);
    k_bh<<<dim3(64, 4), dim3(512), 0, stream>>>(x, Wq, Wk, bk, Ws, ws);
    k_ov<<<dim3(64, 4), dim3(256), 0, stream>>>(Wv, bv, Wo, bo, ws, out);
}